// Round 5
// baseline (266.576 us; speedup 1.0000x reference)
//
#include <hip/hip_runtime.h>
#include <hip/hip_bf16.h>
#include <stdint.h>

#define NR 384          // total rows
#define DD 73728        // C*H*W
#define PDV 16          // N_PARTS * N_DATASETS
#define BSV 192         // batch size
#define KSPLIT 128      // split-K factor (768 blocks = 3/CU)
#define KCH 576         // DD / KSPLIT
#define BK 96           // K-tile per iteration (6 iters/block)
#define RS 104          // LDS row stride in bf16 (208 B: 16B-aligned, 2-way banks)

typedef __bf16 bf16;
typedef __attribute__((ext_vector_type(4))) __bf16 bf16x4;
typedef __attribute__((ext_vector_type(8))) __bf16 bf16x8;
typedef __attribute__((ext_vector_type(4))) float f32x4;

// ---------------------------------------------------------------- kernel 1
// Fused demean + cast + partial Gram, store-side demean into padded bf16 LDS.
// Gp[ks][tile][128][128] = (X-M)_tileA * (X-M)_tileB^T over K chunk ks.
__global__ __launch_bounds__(256, 3) void k_gram(const float* __restrict__ X,
                                                 const float* __restrict__ M,
                                                 float* __restrict__ Gp) {
    __shared__ bf16 ash[128 * RS];   // 26 KB
    __shared__ bf16 bsh[128 * RS];   // 26 KB
    const int tid  = threadIdx.x;
    const int lane = tid & 63;
    const int w    = tid >> 6;
    const int quad = lane >> 4;
    const int l15  = lane & 15;
    const int wm   = w & 1, wn = w >> 1;

    int bx   = blockIdx.x;
    int tile = bx % 6;
    int ks   = bx / 6;
    int tm = (tile < 3) ? 0 : ((tile < 5) ? 1 : 2);
    int tn = (tile < 3) ? tile : ((tile < 5) ? (tile - 2) : 2);
    const float* Xa = X + (size_t)(tm * 128) * DD;
    const float* Xb = X + (size_t)(tn * 128) * DD;
    size_t k0 = (size_t)ks * KCH;

    f32x4 acc[4][4];
#pragma unroll
    for (int i = 0; i < 4; ++i)
#pragma unroll
        for (int j = 0; j < 4; ++j) acc[i][j] = (f32x4){0.f, 0.f, 0.f, 0.f};

    for (int it = 0; it < 6; ++it) {
        size_t kbase = k0 + it * BK;
        __syncthreads();   // prior iter's LDS reads done before overwrite
        // stage 2 tiles x 128 rows x 96 floats; demean once, store bf16.
        // flat idx = l*256+tid -> row = idx/24, kseg = idx%24 (coalesced:
        // 24 consecutive lanes cover one row's 96 floats).
#pragma unroll
        for (int l = 0; l < 12; ++l) {
            int idx  = l * 256 + tid;
            int row  = idx / 24;
            int kseg = idx - row * 24;
            size_t gk = kbase + kseg * 4;
            const float4 m4 = *(const float4*)(M + (size_t)((row >> 2) & 3) * DD + gk);
            const float4 xa = *(const float4*)(Xa + (size_t)row * DD + gk);
            const float4 xb = *(const float4*)(Xb + (size_t)row * DD + gk);
            bf16x4 za, zb;
            za[0] = (bf16)(xa.x - m4.x); za[1] = (bf16)(xa.y - m4.y);
            za[2] = (bf16)(xa.z - m4.z); za[3] = (bf16)(xa.w - m4.w);
            zb[0] = (bf16)(xb.x - m4.x); zb[1] = (bf16)(xb.y - m4.y);
            zb[2] = (bf16)(xb.z - m4.z); zb[3] = (bf16)(xb.w - m4.w);
            *(bf16x4*)&ash[row * RS + kseg * 4] = za;
            *(bf16x4*)&bsh[row * RS + kseg * 4] = zb;
        }
        __syncthreads();

#pragma unroll
        for (int c = 0; c < 3; ++c) {        // 3 k-chunks of 32
            bf16x8 af[4], bfv[4];
#pragma unroll
            for (int i = 0; i < 4; ++i) {
                int r = wm * 64 + i * 16 + l15;
                af[i] = *(const bf16x8*)&ash[r * RS + c * 32 + quad * 8];
            }
#pragma unroll
            for (int j = 0; j < 4; ++j) {
                int r = wn * 64 + j * 16 + l15;
                bfv[j] = *(const bf16x8*)&bsh[r * RS + c * 32 + quad * 8];
            }
#pragma unroll
            for (int i = 0; i < 4; ++i)
#pragma unroll
                for (int j = 0; j < 4; ++j)
                    acc[i][j] = __builtin_amdgcn_mfma_f32_16x16x32_bf16(
                        af[i], bfv[j], acc[i][j], 0, 0, 0);
        }
    }

    float* gp = Gp + ((size_t)(ks * 6 + tile) << 14);
#pragma unroll
    for (int i = 0; i < 4; ++i) {
        int lr0 = wm * 64 + i * 16 + quad * 4;
#pragma unroll
        for (int j = 0; j < 4; ++j) {
            int lc = wn * 64 + j * 16 + l15;
#pragma unroll
            for (int r = 0; r < 4; ++r)
                gp[(lr0 + r) * 128 + lc] = acc[i][j][r];
        }
    }
}

// ---------------------------------------------------------------- kernel 2
// Reduce partials -> full symmetric G + per-row inverse norm. Zeroes out[0].
__global__ __launch_bounds__(256) void k_red(const float* __restrict__ Gp,
                                             float* __restrict__ G,
                                             float* __restrict__ invn,
                                             float* __restrict__ out) {
    int t    = blockIdx.x * 256 + threadIdx.x;
    if (t == 0) out[0] = 0.0f;
    int tile = t >> 14;
    int idx  = t & 16383;
    int lr   = idx >> 7, lc = idx & 127;
    const float* p = Gp + ((size_t)tile << 14) + idx;
    float s = 0.0f;
#pragma unroll 8
    for (int ks = 0; ks < KSPLIT; ++ks) s += p[(size_t)ks * 98304];
    int tm = (tile < 3) ? 0 : ((tile < 5) ? 1 : 2);
    int tn = (tile < 3) ? tile : ((tile < 5) ? (tile - 2) : 2);
    int a = tm * 128 + lr, b = tn * 128 + lc;
    G[(size_t)a * NR + b] = s;
    G[(size_t)b * NR + a] = s;
    if (a == b) invn[a] = 1.0f / fmaxf(sqrtf(s), 1e-6f);
}

// ---------------------------------------------------------------- kernel 3
// One wave per row a: Ds[a] = sum_b mask*exp(S[a][b]); then lane 0 adds this
// row's 4 pair-slot terms  (-num + log(exp(num)+Ds[a]))  to out.
__global__ __launch_bounds__(256) void k_dsum(const float* __restrict__ G,
                                              const float* __restrict__ invn,
                                              float* __restrict__ out) {
    const int lane = threadIdx.x & 63;
    const int a    = blockIdx.x * 4 + (threadIdx.x >> 6);
    float ia  = invn[a];
    int arem  = a & 15;
    float acc = 0.0f;
    for (int b = lane; b < NR; b += 64) {
        float s = G[(size_t)a * NR + b] * ia * invn[b] * 10.0f;
        if ((b & 15) != arem) acc += expf(s);
    }
#pragma unroll
    for (int o = 32; o > 0; o >>= 1) acc += __shfl_down(acc, o);
    if (lane == 0) {
        float Dsa = acc;
        int pr[4];
        if (a < 16)       { pr[0] = 192 + a; pr[1] = a + 16;  pr[2] = a + 192; pr[3] = a + 368; }
        else if (a < 192) { pr[0] = 192 + a; pr[1] = a + 16;  pr[2] = a + 192; pr[3] = a - 16; }
        else if (a < 368) { pr[0] = a - 192; pr[1] = a + 16;  pr[2] = a - 192; pr[3] = a - 16; }
        else              { pr[0] = a - 192; pr[1] = a - 368; pr[2] = a - 192; pr[3] = a - 16; }
        float t = 0.0f;
#pragma unroll
        for (int s = 0; s < 4; ++s) {
            int b = pr[s];
            float num = G[(size_t)a * NR + b] * ia * invn[b] * 10.0f;
            t += -num + logf(expf(num) + Dsa);
        }
        atomicAdd(out, t * (1.0f / 576.0f));   // / (N_TRANSFORMS*3*BS)
    }
}

// ---------------------------------------------------------------- launch
extern "C" void kernel_launch(void* const* d_in, const int* in_sizes, int n_in,
                              void* d_out, int out_size, void* d_ws, size_t ws_size,
                              hipStream_t stream) {
    const float* X = (const float*)d_in[0];
    const float* M = (const float*)d_in[1];
    float* out = (float*)d_out;

    char* ws = (char*)d_ws;
    float* Gp   = (float*)ws;                                  // 50.3 MB
    float* G    = Gp + (size_t)KSPLIT * 6 * 16384;             // 590 KB
    float* invn = G + (size_t)NR * NR;

    k_gram<<<dim3(6 * KSPLIT), dim3(256), 0, stream>>>(X, M, Gp);
    k_red<<<dim3(384), dim3(256), 0, stream>>>(Gp, G, invn, out);
    k_dsum<<<dim3(NR / 4), dim3(256), 0, stream>>>(G, invn, out);
}

// Round 6
// 197.826 us; speedup vs baseline: 1.3475x; 1.3475x over previous
//
#include <hip/hip_runtime.h>
#include <hip/hip_bf16.h>
#include <stdint.h>

#define NR 384          // total rows
#define DD 73728        // C*H*W
#define PDV 16          // N_PARTS * N_DATASETS
#define BSV 192         // batch size
#define KSPLIT 128      // split-K factor (768 blocks = 3/CU)
#define KCH 576         // DD / KSPLIT
#define BK 32           // K-tile per iteration
#define NIT 18          // KCH / BK
#define RS 40           // LDS row stride bf16 (80 B = 20 banks, 16B-aligned)

typedef __bf16 bf16;
typedef __attribute__((ext_vector_type(4))) __bf16 bf16x4;
typedef __attribute__((ext_vector_type(8))) __bf16 bf16x8;
typedef __attribute__((ext_vector_type(4))) float f32x4;

// ---------------------------------------------------------------- kernel 1
// Fused demean + cast + partial Gram, software-pipelined:
//   M slice staged to LDS once; X prefetched to registers one iter ahead;
//   demean+cvt at ds_write time (once per element); diagonal tiles skip B.
__global__ __launch_bounds__(256, 3) void k_gram(const float* __restrict__ X,
                                                 const float* __restrict__ M,
                                                 float* __restrict__ Gp) {
    __shared__ float msh[4 * KCH];     // 9.2 KB: this block's M k-slice
    __shared__ bf16 ash[128 * RS];     // 10 KB
    __shared__ bf16 bsh[128 * RS];     // 10 KB
    const int tid  = threadIdx.x;
    const int lane = tid & 63;
    const int w    = tid >> 6;
    const int quad = lane >> 4;
    const int l15  = lane & 15;
    const int wm   = w & 1, wn = w >> 1;
    const int srow = tid >> 3;         // staging row base 0..31
    const int fseg = tid & 7;          // 16B segment within 128B row-chunk

    int tile = blockIdx.x % 6;
    int ks   = blockIdx.x / 6;
    int tm = (tile < 3) ? 0 : ((tile < 5) ? 1 : 2);
    int tn = (tile < 3) ? tile : ((tile < 5) ? (tile - 2) : 2);
    const bool diag = (tm == tn);
    const float* Xa = X + (size_t)(tm * 128) * DD;
    const float* Xb = X + (size_t)(tn * 128) * DD;
    const bf16* bbase = diag ? ash : bsh;
    size_t k0 = (size_t)ks * KCH;

    // ---- stage M slice once: 4 datasets x 576 floats
    for (int i = tid; i < 4 * 144; i += 256) {
        int ds = i / 144;
        int c  = (i - ds * 144) * 4;
        *(float4*)&msh[ds * KCH + c] = *(const float4*)(M + (size_t)ds * DD + k0 + c);
    }

    f32x4 acc[4][4];
#pragma unroll
    for (int i = 0; i < 4; ++i)
#pragma unroll
        for (int j = 0; j < 4; ++j) acc[i][j] = (f32x4){0.f, 0.f, 0.f, 0.f};

    float4 xa[4], xb[4];
    auto load_regs = [&](int it) {
        size_t gk = k0 + (size_t)it * BK + fseg * 4;
#pragma unroll
        for (int p = 0; p < 4; ++p) {
            int row = p * 32 + srow;
            xa[p] = *(const float4*)(Xa + (size_t)row * DD + gk);
            if (!diag) xb[p] = *(const float4*)(Xb + (size_t)row * DD + gk);
        }
    };
    auto write_tiles = [&](int it) {
        int kc = it * BK + fseg * 4;
#pragma unroll
        for (int p = 0; p < 4; ++p) {
            int row = p * 32 + srow;
            float4 m4 = *(const float4*)&msh[((row >> 2) & 3) * KCH + kc];
            bf16x4 za;
            za[0] = (bf16)(xa[p].x - m4.x); za[1] = (bf16)(xa[p].y - m4.y);
            za[2] = (bf16)(xa[p].z - m4.z); za[3] = (bf16)(xa[p].w - m4.w);
            *(bf16x4*)&ash[row * RS + fseg * 4] = za;
            if (!diag) {
                bf16x4 zb;
                zb[0] = (bf16)(xb[p].x - m4.x); zb[1] = (bf16)(xb[p].y - m4.y);
                zb[2] = (bf16)(xb[p].z - m4.z); zb[3] = (bf16)(xb[p].w - m4.w);
                *(bf16x4*)&bsh[row * RS + fseg * 4] = zb;
            }
        }
    };

    load_regs(0);
    __syncthreads();        // msh visible (and iter-0 loads drained)
    write_tiles(0);

    for (int it = 0; it < NIT; ++it) {
        __syncthreads();    // tile `it` published
        if (it + 1 < NIT) load_regs(it + 1);   // prefetch behind compute
        bf16x8 af[4], bfv[4];
#pragma unroll
        for (int i = 0; i < 4; ++i) {
            int r = wm * 64 + i * 16 + l15;
            af[i] = *(const bf16x8*)&ash[r * RS + quad * 8];
        }
#pragma unroll
        for (int j = 0; j < 4; ++j) {
            int r = wn * 64 + j * 16 + l15;
            bfv[j] = *(const bf16x8*)&bbase[r * RS + quad * 8];
        }
#pragma unroll
        for (int i = 0; i < 4; ++i)
#pragma unroll
            for (int j = 0; j < 4; ++j)
                acc[i][j] = __builtin_amdgcn_mfma_f32_16x16x32_bf16(
                    af[i], bfv[j], acc[i][j], 0, 0, 0);
        __syncthreads();    // reads of tile `it` done
        if (it + 1 < NIT) write_tiles(it + 1);
    }

    float* gp = Gp + ((size_t)(ks * 6 + tile) << 14);
#pragma unroll
    for (int i = 0; i < 4; ++i) {
        int lr0 = wm * 64 + i * 16 + quad * 4;
#pragma unroll
        for (int j = 0; j < 4; ++j) {
            int lc = wn * 64 + j * 16 + l15;
#pragma unroll
            for (int r = 0; r < 4; ++r)
                gp[(lr0 + r) * 128 + lc] = acc[i][j][r];
        }
    }
}

// ---------------------------------------------------------------- kernel 2
// Reduce partials -> full symmetric G + per-row inverse norm. Zeroes out[0].
__global__ __launch_bounds__(256) void k_red(const float* __restrict__ Gp,
                                             float* __restrict__ G,
                                             float* __restrict__ invn,
                                             float* __restrict__ out) {
    int t    = blockIdx.x * 256 + threadIdx.x;
    if (t == 0) out[0] = 0.0f;
    int tile = t >> 14;
    int idx  = t & 16383;
    int lr   = idx >> 7, lc = idx & 127;
    const float* p = Gp + ((size_t)tile << 14) + idx;
    float s = 0.0f;
#pragma unroll 8
    for (int ks = 0; ks < KSPLIT; ++ks) s += p[(size_t)ks * 98304];
    int tm = (tile < 3) ? 0 : ((tile < 5) ? 1 : 2);
    int tn = (tile < 3) ? tile : ((tile < 5) ? (tile - 2) : 2);
    int a = tm * 128 + lr, b = tn * 128 + lc;
    G[(size_t)a * NR + b] = s;
    G[(size_t)b * NR + a] = s;
    if (a == b) invn[a] = 1.0f / fmaxf(sqrtf(s), 1e-6f);
}

// ---------------------------------------------------------------- kernel 3
// One wave per row a: Ds[a] = sum_b mask*exp(S[a][b]); then lane 0 adds this
// row's 4 pair-slot terms  (-num + log(exp(num)+Ds[a]))  to out.
__global__ __launch_bounds__(256) void k_dsum(const float* __restrict__ G,
                                              const float* __restrict__ invn,
                                              float* __restrict__ out) {
    const int lane = threadIdx.x & 63;
    const int a    = blockIdx.x * 4 + (threadIdx.x >> 6);
    float ia  = invn[a];
    int arem  = a & 15;
    float acc = 0.0f;
    for (int b = lane; b < NR; b += 64) {
        float s = G[(size_t)a * NR + b] * ia * invn[b] * 10.0f;
        if ((b & 15) != arem) acc += expf(s);
    }
#pragma unroll
    for (int o = 32; o > 0; o >>= 1) acc += __shfl_down(acc, o);
    if (lane == 0) {
        float Dsa = acc;
        int pr[4];
        if (a < 16)       { pr[0] = 192 + a; pr[1] = a + 16;  pr[2] = a + 192; pr[3] = a + 368; }
        else if (a < 192) { pr[0] = 192 + a; pr[1] = a + 16;  pr[2] = a + 192; pr[3] = a - 16; }
        else if (a < 368) { pr[0] = a - 192; pr[1] = a + 16;  pr[2] = a - 192; pr[3] = a - 16; }
        else              { pr[0] = a - 192; pr[1] = a - 368; pr[2] = a - 192; pr[3] = a - 16; }
        float t = 0.0f;
#pragma unroll
        for (int s = 0; s < 4; ++s) {
            int b = pr[s];
            float num = G[(size_t)a * NR + b] * ia * invn[b] * 10.0f;
            t += -num + logf(expf(num) + Dsa);
        }
        atomicAdd(out, t * (1.0f / 576.0f));   // / (N_TRANSFORMS*3*BS)
    }
}

// ---------------------------------------------------------------- launch
extern "C" void kernel_launch(void* const* d_in, const int* in_sizes, int n_in,
                              void* d_out, int out_size, void* d_ws, size_t ws_size,
                              hipStream_t stream) {
    const float* X = (const float*)d_in[0];
    const float* M = (const float*)d_in[1];
    float* out = (float*)d_out;

    char* ws = (char*)d_ws;
    float* Gp   = (float*)ws;                                  // 50.3 MB
    float* G    = Gp + (size_t)KSPLIT * 6 * 16384;             // 590 KB
    float* invn = G + (size_t)NR * NR;

    k_gram<<<dim3(6 * KSPLIT), dim3(256), 0, stream>>>(X, M, Gp);
    k_red<<<dim3(384), dim3(256), 0, stream>>>(Gp, G, invn, out);
    k_dsum<<<dim3(NR / 4), dim3(256), 0, stream>>>(G, invn, out);
}